// Round 2
// baseline (10247.678 us; speedup 1.0000x reference)
//
#include <hip/hip_runtime.h>

#define DI __device__ __forceinline__

typedef __attribute__((ext_vector_type(8))) short s16x8;
typedef __attribute__((ext_vector_type(4))) float f32x4;

constexpr int BB = 32, TT = 512, NH = 1024, NG = 4096, KX = 512, KT = 1536;
constexpr int NT0 = 2048, NT1 = 512;

// d_out element offsets (f32): dec0, dec1, h_t, c_t
constexpr size_t OFF_DEC1 = (size_t)BB * TT * NT0;
constexpr size_t OFF_H    = OFF_DEC1 + (size_t)BB * TT * NT1;
constexpr size_t OFF_C    = OFF_H + (size_t)BB * NH;

// workspace byte offsets (all 256-aligned)
constexpr size_t WS_WCAT = 0;                                   // bf16 [4096][1536] = Wih||Whh
constexpr size_t WS_WD0  = WS_WCAT + (size_t)NG * KT * 2;       // bf16 [2048][1024]
constexpr size_t WS_WD1  = WS_WD0 + (size_t)NT0 * NH * 2;       // bf16 [512][1024]
constexpr size_t WS_XE   = WS_WD1 + (size_t)NT1 * NH * 2;       // bf16 [T][32][512] embedded x
constexpr size_t WS_HSX  = WS_XE + (size_t)TT * BB * KX * 2;    // bf16 [T+1][32][1024] h history
constexpr size_t WS_BIAS = WS_HSX + (size_t)(TT + 1) * BB * NH * 2; // f32 [4096] b_ih+b_hh
constexpr size_t WS_CNT  = WS_BIAS + (size_t)NG * 4;            // u32 barrier counter

DI unsigned short f2bf(float f) {  // round-to-nearest-even f32 -> bf16
  unsigned u = __float_as_uint(f);
  u += 0x7fffu + ((u >> 16) & 1u);
  return (unsigned short)(u >> 16);
}

// ---------------- prep kernels ----------------

__global__ __launch_bounds__(256) void k_wcat(const float* __restrict__ Wih,
                                              const float* __restrict__ Whh,
                                              unsigned short* __restrict__ Wcat) {
  int n = blockIdx.x;  // 0..4095
  for (int k = threadIdx.x; k < KT; k += 256) {
    float v = (k < KX) ? Wih[(size_t)n * KX + k] : Whh[(size_t)n * NH + (k - KX)];
    Wcat[(size_t)n * KT + k] = f2bf(v);
  }
}

__global__ __launch_bounds__(256) void k_wd(const float* __restrict__ Wd0,
                                            const float* __restrict__ Wd1,
                                            unsigned short* __restrict__ Wd0b,
                                            unsigned short* __restrict__ Wd1b) {
  int bid = blockIdx.x;  // 0..2559
  const float* src;
  unsigned short* dst;
  if (bid < NT0) { src = Wd0 + (size_t)bid * NH; dst = Wd0b + (size_t)bid * NH; }
  else           { src = Wd1 + (size_t)(bid - NT0) * NH; dst = Wd1b + (size_t)(bid - NT0) * NH; }
  for (int k = threadIdx.x; k < NH; k += 256) dst[k] = f2bf(src[k]);
}

__global__ __launch_bounds__(256) void k_misc(const float* __restrict__ bih,
                                              const float* __restrict__ bhh,
                                              const float* __restrict__ h0,
                                              float* __restrict__ bias,
                                              unsigned short* __restrict__ hsx,
                                              unsigned* __restrict__ cnt) {
  int i = blockIdx.x * 256 + threadIdx.x;
  if (i < NG) bias[i] = bih[i] + bhh[i];
  else if (i < NG + BB * NH) { int j = i - NG; hsx[j] = f2bf(h0[j]); }
  else if (i == NG + BB * NH) *cnt = 0u;
}

__global__ __launch_bounds__(64) void k_embed(const int* __restrict__ tok0,
                                              const int* __restrict__ tok1,
                                              const float* __restrict__ emb0,
                                              const float* __restrict__ emb1,
                                              unsigned short* __restrict__ xe) {
  int r = blockIdx.x;        // r = t*32 + b
  int t = r >> 5, b = r & 31;
  int i = threadIdx.x;       // 0..63
  int a0 = tok0[b * TT + t], a1 = tok1[b * TT + t];
  const float4* e0 = (const float4*)(emb0 + (size_t)a0 * 256);
  const float4* e1 = (const float4*)(emb1 + (size_t)a1 * 256);
  float4 v0 = e0[i], v1 = e1[i];
  unsigned short* dst = xe + (size_t)r * KX;
  dst[i * 4 + 0] = f2bf(v0.x); dst[i * 4 + 1] = f2bf(v0.y);
  dst[i * 4 + 2] = f2bf(v0.z); dst[i * 4 + 3] = f2bf(v0.w);
  dst[256 + i * 4 + 0] = f2bf(v1.x); dst[256 + i * 4 + 1] = f2bf(v1.y);
  dst[256 + i * 4 + 2] = f2bf(v1.z); dst[256 + i * 4 + 3] = f2bf(v1.w);
}

// ---------------- persistent LSTM ----------------
// 64 blocks x 256 threads (4 waves). Wave = gate g. Block owns 16 hidden units.
// Each wave computes gate rows n = g*NH + blk*16 + [0,16) for all 32 batch rows
// (two 16-row M-tiles). The block's entire weight slice (4 gates x 16 rows x
// 1536 K, bf16) lives in REGISTERS: 48 B-fragments/lane = 192 VGPRs, immune to
// the per-step L2 invalidate the cross-XCD acquire fence performs.
__global__ __launch_bounds__(256, 1) void k_lstm(const unsigned short* __restrict__ xe,
                                                 const unsigned short* __restrict__ Wcat,
                                                 const float* __restrict__ bias,
                                                 unsigned short* __restrict__ hsx,
                                                 const float* __restrict__ c0,
                                                 float* __restrict__ out_h,
                                                 float* __restrict__ out_c,
                                                 unsigned* cnt) {
  __shared__ char hbuf[65536];          // h_t tile bf16 [32][1024], XOR-swizzled
  __shared__ float gbuf[4 * 32 * 17];   // [gate][batch][16+1 pad] gate pre-activations

  const int tid  = threadIdx.x;
  const int blk  = blockIdx.x;
  const int lane = tid & 63;
  const int g    = tid >> 6;           // wave index = gate: 0=i 1=f 2=g 3=o
  const int col  = lane & 15;
  const int kgrp = lane >> 4;
  const int n    = g * NH + blk * 16 + col;
  const float bias_v = bias[n];

  // --- preload W fragments into registers (static-indexed -> VGPRs) ---
  s16x8 wf[48];
  {
    const unsigned short* wbase = Wcat + (size_t)n * KT + kgrp * 8;
    #pragma unroll
    for (int j = 0; j < 48; ++j) wf[j] = *(const s16x8*)(wbase + j * 32);
  }

  // pointwise ownership: thread handles (pb, 2*pm) and (pb, 2*pm+1)
  const int pb = tid >> 3;             // batch 0..31
  const int pm = tid & 7;
  const int hid0 = blk * 16 + 2 * pm;
  float c_0 = c0[pb * NH + hid0];
  float c_1 = c0[pb * NH + hid0 + 1];

  const int arow0 = col;               // M-tile 0 batch row
  const int arow1 = 16 + col;          // M-tile 1 batch row
  const int ax0 = (arow0 & 7) << 4;
  const int ax1 = (arow1 & 7) << 4;

  unsigned* hsx32 = (unsigned*)hsx;

  for (int t = 0; t < TT; ++t) {
    // 1. issue h_t loads (64KB/block; latency partially hidden under x-part)
    const unsigned short* hsrc = hsx + (size_t)t * (BB * NH);
    s16x8 hv[16];
    #pragma unroll
    for (int it = 0; it < 16; ++it) hv[it] = *(const s16x8*)(hsrc + (it * 256 + tid) * 8);

    // 2. x-part: K = 0..511, W_ih fragments from registers
    f32x4 acc0 = {bias_v, bias_v, bias_v, bias_v};
    f32x4 acc1 = acc0;
    const unsigned short* x0 = xe + ((size_t)t * BB + arow0) * KX + kgrp * 8;
    const unsigned short* x1 = xe + ((size_t)t * BB + arow1) * KX + kgrp * 8;
    #pragma unroll
    for (int j = 0; j < 16; ++j) {
      s16x8 a0 = *(const s16x8*)(x0 + j * 32);
      acc0 = __builtin_amdgcn_mfma_f32_16x16x32_bf16(a0, wf[j], acc0, 0, 0, 0);
      s16x8 a1 = *(const s16x8*)(x1 + j * 32);
      acc1 = __builtin_amdgcn_mfma_f32_16x16x32_bf16(a1, wf[j], acc1, 0, 0, 0);
    }

    // 3. stage h_t -> LDS, XOR swizzle (safe: barrier syncs guard prior reads)
    #pragma unroll
    for (int it = 0; it < 16; ++it) {
      int ch = it * 256 + tid;          // 4096 chunks of 16B
      int row = ch >> 7;
      int boff = (ch & 127) << 4;
      *(s16x8*)(hbuf + row * 2048 + (boff ^ ((row & 7) << 4))) = hv[it];
    }
    __syncthreads();

    // 4. h-part: K = 512..1535, A from swizzled LDS, W_hh from registers
    const char* hb0 = hbuf + arow0 * 2048;
    const char* hb1 = hbuf + arow1 * 2048;
    #pragma unroll
    for (int j = 0; j < 32; ++j) {
      int boff = (j * 32 + kgrp * 8) << 1;
      s16x8 a0 = *(const s16x8*)(hb0 + (boff ^ ax0));
      acc0 = __builtin_amdgcn_mfma_f32_16x16x32_bf16(a0, wf[16 + j], acc0, 0, 0, 0);
      s16x8 a1 = *(const s16x8*)(hb1 + (boff ^ ax1));
      acc1 = __builtin_amdgcn_mfma_f32_16x16x32_bf16(a1, wf[16 + j], acc1, 0, 0, 0);
    }

    // 5. gate pre-activations -> gbuf[g][brow][col] (pad 17 -> ~2-way max)
    #pragma unroll
    for (int i = 0; i < 4; ++i) {
      gbuf[g * 544 + (kgrp * 4 + i) * 17 + col] = acc0[i];
      gbuf[g * 544 + (16 + kgrp * 4 + i) * 17 + col] = acc1[i];
    }
    __syncthreads();

    // 6. pointwise: 2 cells per thread
    {
      const float* gb = gbuf + pb * 17 + 2 * pm;
      float gi0 = gb[0 * 544], gi1 = gb[0 * 544 + 1];
      float gf0 = gb[1 * 544], gf1 = gb[1 * 544 + 1];
      float gg0 = gb[2 * 544], gg1 = gb[2 * 544 + 1];
      float go0 = gb[3 * 544], go1 = gb[3 * 544 + 1];
      float iv0 = 1.f / (1.f + __expf(-gi0)), iv1 = 1.f / (1.f + __expf(-gi1));
      float fv0 = 1.f / (1.f + __expf(-gf0)), fv1 = 1.f / (1.f + __expf(-gf1));
      float gv0 = tanhf(gg0),                 gv1 = tanhf(gg1);
      float ov0 = 1.f / (1.f + __expf(-go0)), ov1 = 1.f / (1.f + __expf(-go1));
      c_0 = fv0 * c_0 + iv0 * gv0;
      c_1 = fv1 * c_1 + iv1 * gv1;
      float h0v = ov0 * tanhf(c_0);
      float h1v = ov1 * tanhf(c_1);
      unsigned pk = (unsigned)f2bf(h0v) | ((unsigned)f2bf(h1v) << 16);
      hsx32[((size_t)(t + 1) * (BB * NH) + pb * NH + hid0) >> 1] = pk;
      if (t == TT - 1) {
        out_h[pb * NH + hid0] = h0v;  out_h[pb * NH + hid0 + 1] = h1v;
        out_c[pb * NH + hid0] = c_0;  out_c[pb * NH + hid0 + 1] = c_1;
      }
    }

    // 7. grid barrier: ONE release fence (wbl2: ~1KB dirty) + relaxed add,
    //    relaxed poll, ONE acquire fence (inv). W is in registers -> immune.
    if (t < TT - 1) {
      __builtin_amdgcn_fence(__ATOMIC_RELEASE, "agent");
      __syncthreads();
      if (tid == 0) {
        __hip_atomic_fetch_add(cnt, 1u, __ATOMIC_RELAXED, __HIP_MEMORY_SCOPE_AGENT);
        while (__hip_atomic_load(cnt, __ATOMIC_RELAXED, __HIP_MEMORY_SCOPE_AGENT) <
               (unsigned)gridDim.x * (unsigned)(t + 1))
          __builtin_amdgcn_s_sleep(1);
      }
      __syncthreads();
      __builtin_amdgcn_fence(__ATOMIC_ACQUIRE, "agent");
    }
  }
}

// ---------------- decoder GEMM: out[b][t][n] = hs[r]·Wb[n] + bd[n], r = t*32+b ----------------

__global__ __launch_bounds__(256) void k_dec(const unsigned short* __restrict__ A,  // [16384][1024]
                                             const unsigned short* __restrict__ Wb, // [N][1024]
                                             const float* __restrict__ bd,
                                             float* __restrict__ out, int N, int gn) {
  __shared__ char smem[32768];  // As [128][64] bf16 swizzled + Bs same at +16384
  const int tid = threadIdx.x;
  const int bid = blockIdx.x;
  const int tm = bid / gn, tn = bid % gn;
  const int lane = tid & 63;
  const int w = tid >> 6;
  const int wr = w >> 1, wc = w & 1;     // 2x2 wave grid, 64x64 subtile each
  const int col = lane & 15, kgrp = lane >> 4;

  f32x4 acc[4][4];
  #pragma unroll
  for (int i = 0; i < 4; ++i)
    #pragma unroll
    for (int j = 0; j < 4; ++j) acc[i][j] = {0.f, 0.f, 0.f, 0.f};

  const unsigned short* Ag = A + (size_t)(tm * 128) * NH;
  const unsigned short* Bg = Wb + (size_t)(tn * 128) * NH;

  for (int kb = 0; kb < 16; ++kb) {
    #pragma unroll
    for (int it = 0; it < 4; ++it) {
      int ch = it * 256 + tid;            // 1024 chunks of 16B each buffer
      int row = ch >> 3;
      int ko = (ch & 7) << 3;
      int lo = row * 128 + ((ko << 1) ^ ((row & 7) << 4));
      *(s16x8*)(smem + lo)         = *(const s16x8*)(Ag + (size_t)row * NH + kb * 64 + ko);
      *(s16x8*)(smem + 16384 + lo) = *(const s16x8*)(Bg + (size_t)row * NH + kb * 64 + ko);
    }
    __syncthreads();
    #pragma unroll
    for (int kk = 0; kk < 64; kk += 32) {
      s16x8 av[4], bv[4];
      #pragma unroll
      for (int mi = 0; mi < 4; ++mi) {
        int row = wr * 64 + mi * 16 + col;
        av[mi] = *(const s16x8*)(smem + row * 128 + (((kk + kgrp * 8) << 1) ^ ((row & 7) << 4)));
      }
      #pragma unroll
      for (int ni = 0; ni < 4; ++ni) {
        int row = wc * 64 + ni * 16 + col;
        bv[ni] = *(const s16x8*)(smem + 16384 + row * 128 + (((kk + kgrp * 8) << 1) ^ ((row & 7) << 4)));
      }
      #pragma unroll
      for (int mi = 0; mi < 4; ++mi)
        #pragma unroll
        for (int ni = 0; ni < 4; ++ni)
          acc[mi][ni] = __builtin_amdgcn_mfma_f32_16x16x32_bf16(av[mi], bv[ni], acc[mi][ni], 0, 0, 0);
    }
    __syncthreads();
  }

  #pragma unroll
  for (int ni = 0; ni < 4; ++ni) {
    int nn = tn * 128 + wc * 64 + ni * 16 + col;
    float bv = bd[nn];
    #pragma unroll
    for (int mi = 0; mi < 4; ++mi) {
      #pragma unroll
      for (int i = 0; i < 4; ++i) {
        int r = tm * 128 + wr * 64 + mi * 16 + kgrp * 4 + i;
        int t = r >> 5, b = r & 31;
        out[((size_t)b * TT + t) * N + nn] = acc[mi][ni][i] + bv;
      }
    }
  }
}

// ---------------- host ----------------

extern "C" void kernel_launch(void* const* d_in, const int* in_sizes, int n_in,
                              void* d_out, int out_size, void* d_ws, size_t ws_size,
                              hipStream_t stream) {
  const int*   tok0 = (const int*)d_in[0];
  const int*   tok1 = (const int*)d_in[1];
  const float* h0   = (const float*)d_in[2];
  const float* c0   = (const float*)d_in[3];
  const float* emb0 = (const float*)d_in[4];
  const float* emb1 = (const float*)d_in[5];
  const float* Wih  = (const float*)d_in[6];
  const float* Whh  = (const float*)d_in[7];
  const float* bih  = (const float*)d_in[8];
  const float* bhh  = (const float*)d_in[9];
  const float* Wd0  = (const float*)d_in[10];
  const float* bd0  = (const float*)d_in[11];
  const float* Wd1  = (const float*)d_in[12];
  const float* bd1  = (const float*)d_in[13];

  unsigned char* ws = (unsigned char*)d_ws;
  unsigned short* Wcat = (unsigned short*)(ws + WS_WCAT);
  unsigned short* Wd0b = (unsigned short*)(ws + WS_WD0);
  unsigned short* Wd1b = (unsigned short*)(ws + WS_WD1);
  unsigned short* xe   = (unsigned short*)(ws + WS_XE);
  unsigned short* hsx  = (unsigned short*)(ws + WS_HSX);
  float* bias = (float*)(ws + WS_BIAS);
  unsigned* cnt = (unsigned*)(ws + WS_CNT);
  float* out = (float*)d_out;

  k_wcat<<<NG, 256, 0, stream>>>(Wih, Whh, Wcat);
  k_wd<<<NT0 + NT1, 256, 0, stream>>>(Wd0, Wd1, Wd0b, Wd1b);
  k_misc<<<145, 256, 0, stream>>>(bih, bhh, h0, bias, hsx, cnt);
  k_embed<<<TT * BB, 64, 0, stream>>>(tok0, tok1, emb0, emb1, xe);
  k_lstm<<<64, 256, 0, stream>>>(xe, Wcat, bias, hsx, c0, out + OFF_H, out + OFF_C, cnt);
  k_dec<<<128 * 16, 256, 0, stream>>>(hsx + BB * NH, Wd0b, bd0, out, NT0, 16);
  k_dec<<<128 * 4, 256, 0, stream>>>(hsx + BB * NH, Wd1b, bd1, out + OFF_DEC1, NT1, 4);
}

// Round 3
// 5187.402 us; speedup vs baseline: 1.9755x; 1.9755x over previous
//
#include <hip/hip_runtime.h>

#define DI __device__ __forceinline__

typedef __attribute__((ext_vector_type(8))) short s16x8;
typedef __attribute__((ext_vector_type(4))) float f32x4;

constexpr int BB = 32, TT = 512, NH = 1024, NG = 4096, KX = 512, KT = 1536;
constexpr int NT0 = 2048, NT1 = 512;

// d_out element offsets (f32): dec0, dec1, h_t, c_t
constexpr size_t OFF_DEC1 = (size_t)BB * TT * NT0;
constexpr size_t OFF_H    = OFF_DEC1 + (size_t)BB * TT * NT1;
constexpr size_t OFF_C    = OFF_H + (size_t)BB * NH;

// workspace byte offsets (all 256-aligned)
constexpr size_t WS_WCAT = 0;                                   // bf16 [4096][1536] = Wih||Whh
constexpr size_t WS_WD0  = WS_WCAT + (size_t)NG * KT * 2;       // bf16 [2048][1024]
constexpr size_t WS_WD1  = WS_WD0 + (size_t)NT0 * NH * 2;       // bf16 [512][1024]
constexpr size_t WS_XE   = WS_WD1 + (size_t)NT1 * NH * 2;       // bf16 [T][32][512] embedded x
constexpr size_t WS_HSX  = WS_XE + (size_t)TT * BB * KX * 2;    // bf16 [T+1][32][1024] h history
constexpr size_t WS_BIAS = WS_HSX + (size_t)(TT + 1) * BB * NH * 2; // f32 [4096] b_ih+b_hh
constexpr size_t WS_CNT  = WS_BIAS + (size_t)NG * 4;            // u32 barrier counter

DI unsigned short f2bf(float f) {  // round-to-nearest-even f32 -> bf16
  unsigned u = __float_as_uint(f);
  u += 0x7fffu + ((u >> 16) & 1u);
  return (unsigned short)(u >> 16);
}

// cache-bypassing (coherence-point) global ops: no wbl2/inv ever needed
DI s16x8 load16_cp(const unsigned short* p) {
  s16x8 d;
  asm volatile("global_load_dwordx4 %0, %1, off sc0 sc1" : "=v"(d) : "v"(p) : "memory");
  return d;
}
DI void store4_cp(unsigned* p, unsigned v) {
  asm volatile("global_store_dword %0, %1, off sc0 sc1" :: "v"(p), "v"(v) : "memory");
}

// ---------------- prep kernels ----------------

__global__ __launch_bounds__(256) void k_wcat(const float* __restrict__ Wih,
                                              const float* __restrict__ Whh,
                                              unsigned short* __restrict__ Wcat) {
  int n = blockIdx.x;  // 0..4095
  for (int k = threadIdx.x; k < KT; k += 256) {
    float v = (k < KX) ? Wih[(size_t)n * KX + k] : Whh[(size_t)n * NH + (k - KX)];
    Wcat[(size_t)n * KT + k] = f2bf(v);
  }
}

__global__ __launch_bounds__(256) void k_wd(const float* __restrict__ Wd0,
                                            const float* __restrict__ Wd1,
                                            unsigned short* __restrict__ Wd0b,
                                            unsigned short* __restrict__ Wd1b) {
  int bid = blockIdx.x;  // 0..2559
  const float* src;
  unsigned short* dst;
  if (bid < NT0) { src = Wd0 + (size_t)bid * NH; dst = Wd0b + (size_t)bid * NH; }
  else           { src = Wd1 + (size_t)(bid - NT0) * NH; dst = Wd1b + (size_t)(bid - NT0) * NH; }
  for (int k = threadIdx.x; k < NH; k += 256) dst[k] = f2bf(src[k]);
}

__global__ __launch_bounds__(256) void k_misc(const float* __restrict__ bih,
                                              const float* __restrict__ bhh,
                                              const float* __restrict__ h0,
                                              float* __restrict__ bias,
                                              unsigned short* __restrict__ hsx,
                                              unsigned* __restrict__ cnt) {
  int i = blockIdx.x * 256 + threadIdx.x;
  if (i < NG) bias[i] = bih[i] + bhh[i];
  else if (i < NG + BB * NH) { int j = i - NG; hsx[j] = f2bf(h0[j]); }
  else if (i == NG + BB * NH) *cnt = 0u;
}

__global__ __launch_bounds__(64) void k_embed(const int* __restrict__ tok0,
                                              const int* __restrict__ tok1,
                                              const float* __restrict__ emb0,
                                              const float* __restrict__ emb1,
                                              unsigned short* __restrict__ xe) {
  int r = blockIdx.x;        // r = t*32 + b
  int t = r >> 5, b = r & 31;
  int i = threadIdx.x;       // 0..63
  int a0 = tok0[b * TT + t], a1 = tok1[b * TT + t];
  const float4* e0 = (const float4*)(emb0 + (size_t)a0 * 256);
  const float4* e1 = (const float4*)(emb1 + (size_t)a1 * 256);
  float4 v0 = e0[i], v1 = e1[i];
  unsigned short* dst = xe + (size_t)r * KX;
  dst[i * 4 + 0] = f2bf(v0.x); dst[i * 4 + 1] = f2bf(v0.y);
  dst[i * 4 + 2] = f2bf(v0.z); dst[i * 4 + 3] = f2bf(v0.w);
  dst[256 + i * 4 + 0] = f2bf(v1.x); dst[256 + i * 4 + 1] = f2bf(v1.y);
  dst[256 + i * 4 + 2] = f2bf(v1.z); dst[256 + i * 4 + 3] = f2bf(v1.w);
}

// ---------------- persistent LSTM ----------------
// 64 blocks x 256 threads (4 waves). Wave = gate g. Block owns 16 hidden units.
// W slice in registers (48 B-fragments/lane). h-exchange via sc0sc1 cache-
// bypassing ops at the coherence point -> ZERO cache-maintenance (no wbl2/inv)
// in the loop. Barrier = vmcnt(0) + relaxed agent atomic add + relaxed poll.
__global__ __launch_bounds__(256, 1) void k_lstm(const unsigned short* __restrict__ xe,
                                                 const unsigned short* __restrict__ Wcat,
                                                 const float* __restrict__ bias,
                                                 unsigned short* __restrict__ hsx,
                                                 const float* __restrict__ c0,
                                                 float* __restrict__ out_h,
                                                 float* __restrict__ out_c,
                                                 unsigned* cnt) {
  __shared__ char hbuf[65536];          // h_t tile bf16 [32][1024], XOR-swizzled
  __shared__ float gbuf[4 * 32 * 17];   // [gate][batch][16+1 pad] gate pre-activations

  const int tid  = threadIdx.x;
  const int blk  = blockIdx.x;
  const int lane = tid & 63;
  const int g    = tid >> 6;           // wave index = gate: 0=i 1=f 2=g 3=o
  const int col  = lane & 15;
  const int kgrp = lane >> 4;
  const int n    = g * NH + blk * 16 + col;
  const float bias_v = bias[n];

  // --- preload W fragments into registers (static-indexed -> VGPRs) ---
  s16x8 wf[48];
  {
    const unsigned short* wbase = Wcat + (size_t)n * KT + kgrp * 8;
    #pragma unroll
    for (int j = 0; j < 48; ++j) wf[j] = *(const s16x8*)(wbase + j * 32);
  }

  // pointwise ownership: thread handles (pb, 2*pm) and (pb, 2*pm+1)
  const int pb = tid >> 3;             // batch 0..31
  const int pm = tid & 7;
  const int hid0 = blk * 16 + 2 * pm;
  float c_0 = c0[pb * NH + hid0];
  float c_1 = c0[pb * NH + hid0 + 1];

  const int arow0 = col;               // M-tile 0 batch row
  const int arow1 = 16 + col;          // M-tile 1 batch row
  const int ax0 = (arow0 & 7) << 4;
  const int ax1 = (arow1 & 7) << 4;

  unsigned* hsx32 = (unsigned*)hsx;

  for (int t = 0; t < TT; ++t) {
    // 1. issue h_t loads from the coherence point (sc0 sc1, no cached copies)
    const unsigned short* hsrc = hsx + (size_t)t * (BB * NH);
    s16x8 hv[16];
    #pragma unroll
    for (int it = 0; it < 16; ++it) hv[it] = load16_cp(hsrc + (it * 256 + tid) * 8);

    // 2. x-part: K = 0..511, W_ih fragments from registers (hides h latency)
    f32x4 acc0 = {bias_v, bias_v, bias_v, bias_v};
    f32x4 acc1 = acc0;
    const unsigned short* x0 = xe + ((size_t)t * BB + arow0) * KX + kgrp * 8;
    const unsigned short* x1 = xe + ((size_t)t * BB + arow1) * KX + kgrp * 8;
    #pragma unroll
    for (int j = 0; j < 16; ++j) {
      s16x8 a0 = *(const s16x8*)(x0 + j * 32);
      acc0 = __builtin_amdgcn_mfma_f32_16x16x32_bf16(a0, wf[j], acc0, 0, 0, 0);
      s16x8 a1 = *(const s16x8*)(x1 + j * 32);
      acc1 = __builtin_amdgcn_mfma_f32_16x16x32_bf16(a1, wf[j], acc1, 0, 0, 0);
    }

    // 3. wait for asm loads (compiler can't track them), stage h -> LDS swizzled
    asm volatile("s_waitcnt vmcnt(0)" ::: "memory");
    #pragma unroll
    for (int it = 0; it < 16; ++it) {
      int ch = it * 256 + tid;          // 4096 chunks of 16B
      int row = ch >> 7;
      int boff = (ch & 127) << 4;
      *(s16x8*)(hbuf + row * 2048 + (boff ^ ((row & 7) << 4))) = hv[it];
    }
    __syncthreads();

    // 4. h-part: K = 512..1535, A from swizzled LDS, W_hh from registers
    const char* hb0 = hbuf + arow0 * 2048;
    const char* hb1 = hbuf + arow1 * 2048;
    #pragma unroll
    for (int j = 0; j < 32; ++j) {
      int boff = (j * 32 + kgrp * 8) << 1;
      s16x8 a0 = *(const s16x8*)(hb0 + (boff ^ ax0));
      acc0 = __builtin_amdgcn_mfma_f32_16x16x32_bf16(a0, wf[16 + j], acc0, 0, 0, 0);
      s16x8 a1 = *(const s16x8*)(hb1 + (boff ^ ax1));
      acc1 = __builtin_amdgcn_mfma_f32_16x16x32_bf16(a1, wf[16 + j], acc1, 0, 0, 0);
    }

    // 5. gate pre-activations -> gbuf[g][brow][col] (pad 17)
    #pragma unroll
    for (int i = 0; i < 4; ++i) {
      gbuf[g * 544 + (kgrp * 4 + i) * 17 + col] = acc0[i];
      gbuf[g * 544 + (16 + kgrp * 4 + i) * 17 + col] = acc1[i];
    }
    __syncthreads();

    // 6. pointwise: 2 cells per thread; h store via sc0sc1 (straight to MALL)
    {
      const float* gb = gbuf + pb * 17 + 2 * pm;
      float gi0 = gb[0 * 544], gi1 = gb[0 * 544 + 1];
      float gf0 = gb[1 * 544], gf1 = gb[1 * 544 + 1];
      float gg0 = gb[2 * 544], gg1 = gb[2 * 544 + 1];
      float go0 = gb[3 * 544], go1 = gb[3 * 544 + 1];
      float iv0 = 1.f / (1.f + __expf(-gi0)), iv1 = 1.f / (1.f + __expf(-gi1));
      float fv0 = 1.f / (1.f + __expf(-gf0)), fv1 = 1.f / (1.f + __expf(-gf1));
      float gv0 = tanhf(gg0),                 gv1 = tanhf(gg1);
      float ov0 = 1.f / (1.f + __expf(-go0)), ov1 = 1.f / (1.f + __expf(-go1));
      c_0 = fv0 * c_0 + iv0 * gv0;
      c_1 = fv1 * c_1 + iv1 * gv1;
      float h0v = ov0 * tanhf(c_0);
      float h1v = ov1 * tanhf(c_1);
      unsigned pk = (unsigned)f2bf(h0v) | ((unsigned)f2bf(h1v) << 16);
      store4_cp(hsx32 + (((size_t)(t + 1) * (BB * NH) + pb * NH + hid0) >> 1), pk);
      if (t == TT - 1) {
        out_h[pb * NH + hid0] = h0v;  out_h[pb * NH + hid0 + 1] = h1v;
        out_c[pb * NH + hid0] = c_0;  out_c[pb * NH + hid0 + 1] = c_1;
      }
    }

    // 7. grid barrier, fence-free: stores acked at coherence point by vmcnt(0);
    //    counter is a relaxed agent atomic (also at coherence point).
    if (t < TT - 1) {
      asm volatile("s_waitcnt vmcnt(0)" ::: "memory");
      __syncthreads();
      if (tid == 0) {
        __hip_atomic_fetch_add(cnt, 1u, __ATOMIC_RELAXED, __HIP_MEMORY_SCOPE_AGENT);
        while (__hip_atomic_load(cnt, __ATOMIC_RELAXED, __HIP_MEMORY_SCOPE_AGENT) <
               (unsigned)gridDim.x * (unsigned)(t + 1))
          __builtin_amdgcn_s_sleep(2);
      }
      __syncthreads();
    }
  }
}

// ---------------- decoder GEMM: out[b][t][n] = hs[r]·Wb[n] + bd[n], r = t*32+b ----------------

__global__ __launch_bounds__(256) void k_dec(const unsigned short* __restrict__ A,  // [16384][1024]
                                             const unsigned short* __restrict__ Wb, // [N][1024]
                                             const float* __restrict__ bd,
                                             float* __restrict__ out, int N, int gn) {
  __shared__ char smem[32768];  // As [128][64] bf16 swizzled + Bs same at +16384
  const int tid = threadIdx.x;
  const int bid = blockIdx.x;
  const int tm = bid / gn, tn = bid % gn;
  const int lane = tid & 63;
  const int w = tid >> 6;
  const int wr = w >> 1, wc = w & 1;     // 2x2 wave grid, 64x64 subtile each
  const int col = lane & 15, kgrp = lane >> 4;

  f32x4 acc[4][4];
  #pragma unroll
  for (int i = 0; i < 4; ++i)
    #pragma unroll
    for (int j = 0; j < 4; ++j) acc[i][j] = {0.f, 0.f, 0.f, 0.f};

  const unsigned short* Ag = A + (size_t)(tm * 128) * NH;
  const unsigned short* Bg = Wb + (size_t)(tn * 128) * NH;

  for (int kb = 0; kb < 16; ++kb) {
    #pragma unroll
    for (int it = 0; it < 4; ++it) {
      int ch = it * 256 + tid;            // 1024 chunks of 16B each buffer
      int row = ch >> 3;
      int ko = (ch & 7) << 3;
      int lo = row * 128 + ((ko << 1) ^ ((row & 7) << 4));
      *(s16x8*)(smem + lo)         = *(const s16x8*)(Ag + (size_t)row * NH + kb * 64 + ko);
      *(s16x8*)(smem + 16384 + lo) = *(const s16x8*)(Bg + (size_t)row * NH + kb * 64 + ko);
    }
    __syncthreads();
    #pragma unroll
    for (int kk = 0; kk < 64; kk += 32) {
      s16x8 av[4], bv[4];
      #pragma unroll
      for (int mi = 0; mi < 4; ++mi) {
        int row = wr * 64 + mi * 16 + col;
        av[mi] = *(const s16x8*)(smem + row * 128 + (((kk + kgrp * 8) << 1) ^ ((row & 7) << 4)));
      }
      #pragma unroll
      for (int ni = 0; ni < 4; ++ni) {
        int row = wc * 64 + ni * 16 + col;
        bv[ni] = *(const s16x8*)(smem + 16384 + row * 128 + (((kk + kgrp * 8) << 1) ^ ((row & 7) << 4)));
      }
      #pragma unroll
      for (int mi = 0; mi < 4; ++mi)
        #pragma unroll
        for (int ni = 0; ni < 4; ++ni)
          acc[mi][ni] = __builtin_amdgcn_mfma_f32_16x16x32_bf16(av[mi], bv[ni], acc[mi][ni], 0, 0, 0);
    }
    __syncthreads();
  }

  #pragma unroll
  for (int ni = 0; ni < 4; ++ni) {
    int nn = tn * 128 + wc * 64 + ni * 16 + col;
    float bv = bd[nn];
    #pragma unroll
    for (int mi = 0; mi < 4; ++mi) {
      #pragma unroll
      for (int i = 0; i < 4; ++i) {
        int r = tm * 128 + wr * 64 + mi * 16 + kgrp * 4 + i;
        int t = r >> 5, b = r & 31;
        out[((size_t)b * TT + t) * N + nn] = acc[mi][ni][i] + bv;
      }
    }
  }
}

// ---------------- host ----------------

extern "C" void kernel_launch(void* const* d_in, const int* in_sizes, int n_in,
                              void* d_out, int out_size, void* d_ws, size_t ws_size,
                              hipStream_t stream) {
  const int*   tok0 = (const int*)d_in[0];
  const int*   tok1 = (const int*)d_in[1];
  const float* h0   = (const float*)d_in[2];
  const float* c0   = (const float*)d_in[3];
  const float* emb0 = (const float*)d_in[4];
  const float* emb1 = (const float*)d_in[5];
  const float* Wih  = (const float*)d_in[6];
  const float* Whh  = (const float*)d_in[7];
  const float* bih  = (const float*)d_in[8];
  const float* bhh  = (const float*)d_in[9];
  const float* Wd0  = (const float*)d_in[10];
  const float* bd0  = (const float*)d_in[11];
  const float* Wd1  = (const float*)d_in[12];
  const float* bd1  = (const float*)d_in[13];

  unsigned char* ws = (unsigned char*)d_ws;
  unsigned short* Wcat = (unsigned short*)(ws + WS_WCAT);
  unsigned short* Wd0b = (unsigned short*)(ws + WS_WD0);
  unsigned short* Wd1b = (unsigned short*)(ws + WS_WD1);
  unsigned short* xe   = (unsigned short*)(ws + WS_XE);
  unsigned short* hsx  = (unsigned short*)(ws + WS_HSX);
  float* bias = (float*)(ws + WS_BIAS);
  unsigned* cnt = (unsigned*)(ws + WS_CNT);
  float* out = (float*)d_out;

  k_wcat<<<NG, 256, 0, stream>>>(Wih, Whh, Wcat);
  k_wd<<<NT0 + NT1, 256, 0, stream>>>(Wd0, Wd1, Wd0b, Wd1b);
  k_misc<<<145, 256, 0, stream>>>(bih, bhh, h0, bias, hsx, cnt);
  k_embed<<<TT * BB, 64, 0, stream>>>(tok0, tok1, emb0, emb1, xe);
  k_lstm<<<64, 256, 0, stream>>>(xe, Wcat, bias, hsx, c0, out + OFF_H, out + OFF_C, cnt);
  k_dec<<<128 * 16, 256, 0, stream>>>(hsx + BB * NH, Wd0b, bd0, out, NT0, 16);
  k_dec<<<128 * 4, 256, 0, stream>>>(hsx + BB * NH, Wd1b, bd1, out + OFF_DEC1, NT1, 4);
}